// Round 2
// baseline (2059.952 us; speedup 1.0000x reference)
//
#include <hip/hip_runtime.h>
#include <stdint.h>

#define R_NODES 256
#define M_SAMP  512
#define S_STEPS 512
#define OUT_N   10

// ---------------- layout detection for bool inputs ----------------
// If bools were uploaded as int32, byte (4f+1) of every element is 0.
// If uploaded as uint8, ~half those bytes are 1.  flag=1 => uint8 layout.
__global__ void detect_layout(const uint8_t* __restrict__ x, int* __restrict__ flag) {
    __shared__ int any;
    if (threadIdx.x == 0) any = 0;
    __syncthreads();
    int acc = 0;
    for (int i = 0; i < 64; ++i)
        acc |= x[(size_t)(threadIdx.x * 64 + i) * 4 + 1];
    if (acc) atomicOr(&any, 1);
    __syncthreads();
    if (threadIdx.x == 0) *flag = any ? 1 : 0;
}

// ---------------- pack x bits: one uint32 per (m,s) ----------------
__global__ void pack_x(const uint8_t* __restrict__ x, const int* __restrict__ flag,
                       uint32_t* __restrict__ xp) {
    const int stride = (*flag) ? 1 : 4;
    const int f = blockIdx.x * blockDim.x + threadIdx.x;      // element idx, M*S*32 total
    const int val = x[(size_t)f * stride];
    const uint64_t mask = __ballot(val != 0);
    const int lane = threadIdx.x & 63;
    if ((lane & 31) == 0) {
        uint32_t w = (lane & 32) ? (uint32_t)(mask >> 32) : (uint32_t)mask;
        xp[f >> 5] = w;
    }
}

// ---------------- build byte-chunk partial-sum table ----------------
// Layout [v][c][j]: T2[(v*32 + c)*256 + j] = sum_{b in v} primes[c*8+b]*W_res[j][c*8+b]
// (uint16, per-chunk max ~12.9K). 4 MB total -> fits one XCD L2.
__global__ void build_T2(const uint8_t* __restrict__ wres, const int* __restrict__ primes,
                         const int* __restrict__ flag, uint16_t* __restrict__ T2) {
    const int v = blockIdx.x;          // 0..255 byte value
    const int c = blockIdx.y;          // 0..31 chunk
    const int j = threadIdx.x;         // 0..255 node
    const int stride = (*flag) ? 1 : 4;
    int sum = 0;
#pragma unroll
    for (int b = 0; b < 8; ++b) {
        if ((v >> b) & 1) {
            const int k = c * 8 + b;
            if (wres[(size_t)(j * 256 + k) * stride]) sum += primes[k];
        }
    }
    T2[((size_t)v * 32 + c) * 256 + j] = (uint16_t)sum;
}

// ---------------- bit-pack the LUT: 256MB int32 -> 8MB bits ----------------
// One uint32 output word per thread; 8x dwordx4 loads, register bit assembly.
__global__ void pack_lut(const int* __restrict__ lut, uint32_t* __restrict__ lp32) {
    const int t = blockIdx.x * blockDim.x + threadIdx.x;   // word idx, 2^21 total
    const int4* src = (const int4*)lut + (size_t)t * 8;
    uint32_t w = 0;
#pragma unroll
    for (int i = 0; i < 8; ++i) {
        const int4 q = src[i];
        w |= (uint32_t)(q.x & 1) << (i * 4 + 0);
        w |= (uint32_t)(q.y & 1) << (i * 4 + 1);
        w |= (uint32_t)(q.z & 1) << (i * 4 + 2);
        w |= (uint32_t)(q.w & 1) << (i * 4 + 3);
    }
    lp32[t] = w;
}

// ---------------- main reservoir scan: one block per sample ----------------
__global__ __launch_bounds__(256) void reservoir_main(
    const uint32_t* __restrict__ xp, const uint16_t* __restrict__ T2,
    const uint64_t* __restrict__ lp, const int* __restrict__ input_nodes,
    const uint8_t* __restrict__ init_res, const int* __restrict__ flag,
    const float* __restrict__ rW, const float* __restrict__ rb,
    float* __restrict__ out)
{
    const int m = blockIdx.x;
    const int j = threadIdx.x;
    const int wid = j >> 6;
    const int lane = j & 63;
    __shared__ uint64_t lmask[2][4];   // double-buffered -> 1 barrier per step
    __shared__ float lout[OUT_N];

    const int stride = (*flag) ? 1 : 4;
    int slot = -1;
#pragma unroll
    for (int i = 0; i < 32; ++i)
        if (input_nodes[i] == j) slot = i;

    int v = init_res[(size_t)j * stride] ? 1 : 0;
    const uint64_t* lrow = lp + (size_t)j * 4096;
    const uint32_t* xrow = xp + m * S_STEPS;
    const uint16_t* tj = T2 + j;       // [v][c][j] layout

    for (int s = 0; s < S_STEPS; ++s) {
        const uint32_t xw = xrow[s];
        if (slot >= 0) v = (xw >> slot) & 1;
        const uint64_t bal = __ballot(v != 0);
        const int p = s & 1;
        if (lane == 0) lmask[p][wid] = bal;
        __syncthreads();
        uint64_t mk0 = lmask[p][0], mk1 = lmask[p][1];
        uint64_t mk2 = lmask[p][2], mk3 = lmask[p][3];

        // force ONE parallel load round: all 32 results live simultaneously
        int tv[32];
#pragma unroll
        for (int c = 0; c < 8; ++c) {
            tv[c]      = tj[(((int)((mk0 >> (c * 8)) & 0xFF)) * 32 + c     ) * 256];
            tv[c + 8]  = tj[(((int)((mk1 >> (c * 8)) & 0xFF)) * 32 + c +  8) * 256];
            tv[c + 16] = tj[(((int)((mk2 >> (c * 8)) & 0xFF)) * 32 + c + 16) * 256];
            tv[c + 24] = tj[(((int)((mk3 >> (c * 8)) & 0xFF)) * 32 + c + 24) * 256];
        }
        int idx = 0;
#pragma unroll
        for (int c = 0; c < 32; ++c) idx += tv[c];

        // non-temporal: keep the 8MB LUT out of L2 so T2 stays L2-resident
        const uint64_t word = __builtin_nontemporal_load(lrow + (idx >> 6));
        v = (int)((word >> (idx & 63)) & 1);
    }

    // readout: out[m][o] = b[o] + sum_j v_j * W[o][j]
    if (j < OUT_N) lout[j] = 0.f;
    __syncthreads();
#pragma unroll
    for (int o = 0; o < OUT_N; ++o) {
        float contrib = v ? rW[o * R_NODES + j] : 0.f;
        for (int off = 32; off > 0; off >>= 1)
            contrib += __shfl_down(contrib, off, 64);
        if (lane == 0) atomicAdd(&lout[o], contrib);
    }
    __syncthreads();
    if (j < OUT_N) out[m * OUT_N + j] = lout[j] + rb[j];
}

extern "C" void kernel_launch(void* const* d_in, const int* in_sizes, int n_in,
                              void* d_out, int out_size, void* d_ws, size_t ws_size,
                              hipStream_t stream) {
    const uint8_t* x        = (const uint8_t*)d_in[0];   // bool [M,S,D,B]
    const int* input_nodes  = (const int*)d_in[1];       // int32 [32]
    const int* lut          = (const int*)d_in[2];       // int32 [256, 2^18]
    const uint8_t* wres     = (const uint8_t*)d_in[3];   // bool [256,256]
    const int* primes       = (const int*)d_in[4];       // int32 [256]
    const uint8_t* init_res = (const uint8_t*)d_in[5];   // bool [256]
    const float* rW         = (const float*)d_in[6];     // f32 [10,256]
    const float* rb         = (const float*)d_in[7];     // f32 [10]
    float* out              = (float*)d_out;             // f32 [512,10]

    uint8_t* ws = (uint8_t*)d_ws;
    int*      flag = (int*)ws;                                        // 4 B
    uint32_t* xp   = (uint32_t*)(ws + 4096);                          // 1 MB
    uint16_t* T2   = (uint16_t*)(ws + 4096 + 1048576);                // 4 MB
    uint64_t* lp   = (uint64_t*)(ws + 4096 + 1048576 + 4194304);      // 8 MB

    detect_layout<<<1, 256, 0, stream>>>(x, flag);
    pack_x<<<(M_SAMP * S_STEPS * 32) / 256, 256, 0, stream>>>(x, flag, xp);
    build_T2<<<dim3(256, 32), 256, 0, stream>>>(wres, primes, flag, T2);
    pack_lut<<<(1 << 21) / 256, 256, 0, stream>>>(lut, (uint32_t*)lp);
    reservoir_main<<<M_SAMP, 256, 0, stream>>>(xp, T2, lp, input_nodes, init_res,
                                               flag, rW, rb, out);
}

// Round 3
// 1521.515 us; speedup vs baseline: 1.3539x; 1.3539x over previous
//
#include <hip/hip_runtime.h>
#include <stdint.h>

#define R_NODES 256
#define M_SAMP  512
#define S_STEPS 512
#define OUT_N   10

// ---------------- layout detection for bool inputs ----------------
// If bools were uploaded as int32, byte (4f+1) of every element is 0.
// If uploaded as uint8, ~half those bytes are 1.  flag=1 => uint8 layout.
__global__ void detect_layout(const uint8_t* __restrict__ x, int* __restrict__ flag) {
    __shared__ int any;
    if (threadIdx.x == 0) any = 0;
    __syncthreads();
    int acc = 0;
    for (int i = 0; i < 64; ++i)
        acc |= x[(size_t)(threadIdx.x * 64 + i) * 4 + 1];
    if (acc) atomicOr(&any, 1);
    __syncthreads();
    if (threadIdx.x == 0) *flag = any ? 1 : 0;
}

// ---------------- pack x bits: one uint32 per (m,s) ----------------
__global__ void pack_x(const uint8_t* __restrict__ x, const int* __restrict__ flag,
                       uint32_t* __restrict__ xp) {
    const int stride = (*flag) ? 1 : 4;
    const int f = blockIdx.x * blockDim.x + threadIdx.x;      // element idx, M*S*32 total
    const int val = x[(size_t)f * stride];
    const uint64_t mask = __ballot(val != 0);
    const int lane = threadIdx.x & 63;
    if ((lane & 31) == 0) {
        uint32_t w = (lane & 32) ? (uint32_t)(mask >> 32) : (uint32_t)mask;
        xp[f >> 5] = w;
    }
}

// ---------------- build byte-chunk partial-sum table ----------------
// Layout [v][c][j]: T2[(v*32 + c)*256 + j] = sum_{b in v} primes[c*8+b]*W_res[j][c*8+b]
// (uint16, per-chunk max ~12.9K). 4 MB total.
__global__ void build_T2(const uint8_t* __restrict__ wres, const int* __restrict__ primes,
                         const int* __restrict__ flag, uint16_t* __restrict__ T2) {
    const int v = blockIdx.x;          // 0..255 byte value
    const int c = blockIdx.y;          // 0..31 chunk
    const int j = threadIdx.x;         // 0..255 node
    const int stride = (*flag) ? 1 : 4;
    int sum = 0;
#pragma unroll
    for (int b = 0; b < 8; ++b) {
        if ((v >> b) & 1) {
            const int k = c * 8 + b;
            if (wres[(size_t)(j * 256 + k) * stride]) sum += primes[k];
        }
    }
    T2[((size_t)v * 32 + c) * 256 + j] = (uint16_t)sum;
}

// ---------------- bit-pack the LUT: 256MB int32 -> 8MB bits ----------------
// Lane-coalesced int4 loads; 4 ballots/iter; lanes 0..7 assemble 8 output
// words via bit-spread. One wave-iteration consumes 256 ints (1 KB).
__device__ __forceinline__ uint32_t spread8(uint32_t x) {
    // bit i of low byte -> bit 4*i
    x = (x | (x << 12)) & 0x000F000Fu;
    x = (x | (x << 6))  & 0x03030303u;
    x = (x | (x << 3))  & 0x11111111u;
    return x;
}
__global__ void pack_lut(const int* __restrict__ lut, uint32_t* __restrict__ lp32) {
    const int lane = threadIdx.x & 63;
    const int gw = blockIdx.x * (blockDim.x >> 6) + (threadIdx.x >> 6); // global wave id, 2048
    const int4* src = (const int4*)lut;
    for (int it = 0; it < 128; ++it) {
        const int chunk = gw * 128 + it;               // 262144 wave-chunks total
        const int4 q = src[(size_t)chunk * 64 + lane]; // coalesced 16B/lane
        const uint64_t b0 = __ballot((q.x & 1) != 0);
        const uint64_t b1 = __ballot((q.y & 1) != 0);
        const uint64_t b2 = __ballot((q.z & 1) != 0);
        const uint64_t b3 = __ballot((q.w & 1) != 0);
        if (lane < 8) {
            const uint32_t B0 = (uint32_t)(b0 >> (8 * lane)) & 0xFF;
            const uint32_t B1 = (uint32_t)(b1 >> (8 * lane)) & 0xFF;
            const uint32_t B2 = (uint32_t)(b2 >> (8 * lane)) & 0xFF;
            const uint32_t B3 = (uint32_t)(b3 >> (8 * lane)) & 0xFF;
            const uint32_t w = spread8(B0) | (spread8(B1) << 1)
                             | (spread8(B2) << 2) | (spread8(B3) << 3);
            lp32[(size_t)chunk * 8 + lane] = w;
        }
    }
}

// ---------------- main reservoir scan: one block per sample ----------------
// __launch_bounds__(256, 2): grid is 512 blocks = 2 blocks/CU = 2 waves/SIMD,
// so occupancy beyond 2 waves/EU is useless -- license ~256 VGPRs so the
// scheduler keeps all 32 T2 loads in flight (round-2 failure: VGPR capped
// at 28 by the default max-occupancy heuristic -> serialized load rounds).
__global__ __launch_bounds__(256, 2) void reservoir_main(
    const uint32_t* __restrict__ xp, const uint16_t* __restrict__ T2,
    const uint64_t* __restrict__ lp, const int* __restrict__ input_nodes,
    const uint8_t* __restrict__ init_res, const int* __restrict__ flag,
    const float* __restrict__ rW, const float* __restrict__ rb,
    float* __restrict__ out)
{
    const int m = blockIdx.x;
    const int j = threadIdx.x;
    const int wid = j >> 6;
    const int lane = j & 63;
    __shared__ uint64_t lmask[2][4];   // double-buffered -> 1 barrier per step
    __shared__ float lout[OUT_N];

    const int stride = (*flag) ? 1 : 4;
    int slot = -1;
#pragma unroll
    for (int i = 0; i < 32; ++i)
        if (input_nodes[i] == j) slot = i;

    int v = init_res[(size_t)j * stride] ? 1 : 0;
    const uint64_t* lrow = lp + (size_t)j * 4096;
    const uint32_t* xrow = xp + m * S_STEPS;
    const uint16_t* tj = T2 + j;       // [v][c][j] layout

    for (int s = 0; s < S_STEPS; ++s) {
        const uint32_t xw = xrow[s];
        if (slot >= 0) v = (xw >> slot) & 1;
        const uint64_t bal = __ballot(v != 0);
        const int p = s & 1;
        if (lane == 0) lmask[p][wid] = bal;
        __syncthreads();
        uint64_t mk0 = lmask[p][0], mk1 = lmask[p][1];
        uint64_t mk2 = lmask[p][2], mk3 = lmask[p][3];

        // one parallel load round: all 32 results live simultaneously
        int tv[32];
#pragma unroll
        for (int c = 0; c < 8; ++c) {
            tv[c]      = tj[(((int)((mk0 >> (c * 8)) & 0xFF)) * 32 + c     ) * 256];
            tv[c + 8]  = tj[(((int)((mk1 >> (c * 8)) & 0xFF)) * 32 + c +  8) * 256];
            tv[c + 16] = tj[(((int)((mk2 >> (c * 8)) & 0xFF)) * 32 + c + 16) * 256];
            tv[c + 24] = tj[(((int)((mk3 >> (c * 8)) & 0xFF)) * 32 + c + 24) * 256];
        }
        int idx = 0;
#pragma unroll
        for (int c = 0; c < 32; ++c) idx += tv[c];

        // plain cached gather (round-2 NT bypass tripled HBM fetch: reverted)
        v = (int)((lrow[idx >> 6] >> (idx & 63)) & 1);
    }

    // readout: out[m][o] = b[o] + sum_j v_j * W[o][j]
    if (j < OUT_N) lout[j] = 0.f;
    __syncthreads();
#pragma unroll
    for (int o = 0; o < OUT_N; ++o) {
        float contrib = v ? rW[o * R_NODES + j] : 0.f;
        for (int off = 32; off > 0; off >>= 1)
            contrib += __shfl_down(contrib, off, 64);
        if (lane == 0) atomicAdd(&lout[o], contrib);
    }
    __syncthreads();
    if (j < OUT_N) out[m * OUT_N + j] = lout[j] + rb[j];
}

extern "C" void kernel_launch(void* const* d_in, const int* in_sizes, int n_in,
                              void* d_out, int out_size, void* d_ws, size_t ws_size,
                              hipStream_t stream) {
    const uint8_t* x        = (const uint8_t*)d_in[0];   // bool [M,S,D,B]
    const int* input_nodes  = (const int*)d_in[1];       // int32 [32]
    const int* lut          = (const int*)d_in[2];       // int32 [256, 2^18]
    const uint8_t* wres     = (const uint8_t*)d_in[3];   // bool [256,256]
    const int* primes       = (const int*)d_in[4];       // int32 [256]
    const uint8_t* init_res = (const uint8_t*)d_in[5];   // bool [256]
    const float* rW         = (const float*)d_in[6];     // f32 [10,256]
    const float* rb         = (const float*)d_in[7];     // f32 [10]
    float* out              = (float*)d_out;             // f32 [512,10]

    uint8_t* ws = (uint8_t*)d_ws;
    int*      flag = (int*)ws;                                        // 4 B
    uint32_t* xp   = (uint32_t*)(ws + 4096);                          // 1 MB
    uint16_t* T2   = (uint16_t*)(ws + 4096 + 1048576);                // 4 MB
    uint64_t* lp   = (uint64_t*)(ws + 4096 + 1048576 + 4194304);      // 8 MB

    detect_layout<<<1, 256, 0, stream>>>(x, flag);
    pack_x<<<(M_SAMP * S_STEPS * 32) / 256, 256, 0, stream>>>(x, flag, xp);
    build_T2<<<dim3(256, 32), 256, 0, stream>>>(wres, primes, flag, T2);
    pack_lut<<<512, 256, 0, stream>>>(lut, (uint32_t*)lp);
    reservoir_main<<<M_SAMP, 256, 0, stream>>>(xp, T2, lp, input_nodes, init_res,
                                               flag, rW, rb, out);
}

// Round 4
// 999.283 us; speedup vs baseline: 2.0614x; 1.5226x over previous
//
#include <hip/hip_runtime.h>
#include <stdint.h>

#define R_NODES 256
#define M_SAMP  512
#define S_STEPS 512
#define OUT_N   10

// ---------------- layout detection for bool inputs ----------------
// If bools were uploaded as int32, byte (4f+1) of every element is 0.
// If uploaded as uint8, ~half those bytes are 1.  flag=1 => uint8 layout.
__global__ void detect_layout(const uint8_t* __restrict__ x, int* __restrict__ flag) {
    __shared__ int any;
    if (threadIdx.x == 0) any = 0;
    __syncthreads();
    int acc = 0;
    for (int i = 0; i < 64; ++i)
        acc |= x[(size_t)(threadIdx.x * 64 + i) * 4 + 1];
    if (acc) atomicOr(&any, 1);
    __syncthreads();
    if (threadIdx.x == 0) *flag = any ? 1 : 0;
}

// ---------------- pack x bits: one uint32 per (m,s) ----------------
__global__ void pack_x(const uint8_t* __restrict__ x, const int* __restrict__ flag,
                       uint32_t* __restrict__ xp) {
    const int stride = (*flag) ? 1 : 4;
    const int f = blockIdx.x * blockDim.x + threadIdx.x;      // element idx, M*S*32 total
    const int val = x[(size_t)f * stride];
    const uint64_t mask = __ballot(val != 0);
    const int lane = threadIdx.x & 63;
    if ((lane & 31) == 0) {
        uint32_t w = (lane & 32) ? (uint32_t)(mask >> 32) : (uint32_t)mask;
        xp[f >> 5] = w;
    }
}

// ---------------- build byte-chunk partial-sum table ----------------
// Layout [v][c][j]: T2[(v*32 + c)*256 + j] = sum_{b in v} primes[c*8+b]*W_res[j][c*8+b]
// (uint16, per-chunk max ~12.9K). 4 MB total.
__global__ void build_T2(const uint8_t* __restrict__ wres, const int* __restrict__ primes,
                         const int* __restrict__ flag, uint16_t* __restrict__ T2) {
    const int v = blockIdx.x;          // 0..255 byte value
    const int c = blockIdx.y;          // 0..31 chunk
    const int j = threadIdx.x;         // 0..255 node
    const int stride = (*flag) ? 1 : 4;
    int sum = 0;
#pragma unroll
    for (int b = 0; b < 8; ++b) {
        if ((v >> b) & 1) {
            const int k = c * 8 + b;
            if (wres[(size_t)(j * 256 + k) * stride]) sum += primes[k];
        }
    }
    T2[((size_t)v * 32 + c) * 256 + j] = (uint16_t)sum;
}

// ---------------- bit-pack the LUT: 256MB int32 -> 8MB bits ----------------
// Lane-coalesced int4 loads; 4 ballots/iter; lanes 0..7 assemble 8 output
// words via bit-spread. One wave-iteration consumes 256 ints (1 KB).
__device__ __forceinline__ uint32_t spread8(uint32_t x) {
    // bit i of low byte -> bit 4*i
    x = (x | (x << 12)) & 0x000F000Fu;
    x = (x | (x << 6))  & 0x03030303u;
    x = (x | (x << 3))  & 0x11111111u;
    return x;
}
__global__ void pack_lut(const int* __restrict__ lut, uint32_t* __restrict__ lp32) {
    const int lane = threadIdx.x & 63;
    const int gw = blockIdx.x * (blockDim.x >> 6) + (threadIdx.x >> 6); // global wave id, 2048
    const int4* src = (const int4*)lut;
    for (int it = 0; it < 128; ++it) {
        const int chunk = gw * 128 + it;               // 262144 wave-chunks total
        const int4 q = src[(size_t)chunk * 64 + lane]; // coalesced 16B/lane
        const uint64_t b0 = __ballot((q.x & 1) != 0);
        const uint64_t b1 = __ballot((q.y & 1) != 0);
        const uint64_t b2 = __ballot((q.z & 1) != 0);
        const uint64_t b3 = __ballot((q.w & 1) != 0);
        if (lane < 8) {
            const uint32_t B0 = (uint32_t)(b0 >> (8 * lane)) & 0xFF;
            const uint32_t B1 = (uint32_t)(b1 >> (8 * lane)) & 0xFF;
            const uint32_t B2 = (uint32_t)(b2 >> (8 * lane)) & 0xFF;
            const uint32_t B3 = (uint32_t)(b3 >> (8 * lane)) & 0xFF;
            const uint32_t w = spread8(B0) | (spread8(B1) << 1)
                             | (spread8(B2) << 2) | (spread8(B3) << 3);
            lp32[(size_t)chunk * 8 + lane] = w;
        }
    }
}

// ---------------- main reservoir scan: one block per sample ----------------
// The 32 (chunk,byte) T2 rows needed each step are BLOCK-UNIFORM (the mask is
// shared), so load them cooperatively: thread t = (rg=t>>5, cg=t&31) loads a
// 4-row x 8-col tile with 4x uint4 loads (one latency round even at low VGPR),
// packed-u16 sums the 4 rows (max 4*12952 = 51808 < 2^16: no field overflow),
// publishes partials to LDS; thread j then sums 8 partials and gathers.
__global__ __launch_bounds__(256, 2) void reservoir_main(
    const uint32_t* __restrict__ xp, const uint16_t* __restrict__ T2,
    const uint64_t* __restrict__ lp, const int* __restrict__ input_nodes,
    const uint8_t* __restrict__ init_res, const int* __restrict__ flag,
    const float* __restrict__ rW, const float* __restrict__ rb,
    float* __restrict__ out)
{
    const int m = blockIdx.x;
    const int t = threadIdx.x;
    const int wid = t >> 6;
    const int lane = t & 63;
    const int rg = t >> 5;      // row group: chunks rg*4 .. rg*4+3
    const int cg = t & 31;      // col group: cols cg*8 .. cg*8+7
    __shared__ uint64_t lmask[4];
    __shared__ uint16_t part[8][256];   // [row-group][node] packed partial sums
    __shared__ float lout[OUT_N];

    const int stride = (*flag) ? 1 : 4;
    int slot = -1;
#pragma unroll
    for (int i = 0; i < 32; ++i)
        if (input_nodes[i] == t) slot = i;

    int v = init_res[(size_t)t * stride] ? 1 : 0;
    const uint64_t* lrow = lp + (size_t)t * 4096;
    const uint32_t* xrow = xp + m * S_STEPS;

    for (int s = 0; s < S_STEPS; ++s) {
        const uint32_t xw = xrow[s];
        if (slot >= 0) v = (xw >> slot) & 1;
        const uint64_t bal = __ballot(v != 0);
        if (lane == 0) lmask[wid] = bal;
        __syncthreads();                                   // B_top
        // this thread's 4 chunks c0..c0+3 live in mask word rg>>1, half rg&1
        const uint64_t mw = lmask[rg >> 1];
        const uint32_t half = (uint32_t)(mw >> ((rg & 1) * 32));
        const int c0 = rg * 4;
        const uint4* a0 = (const uint4*)(T2 + (size_t)(((int)( half        & 0xFF) * 32 + c0 + 0) * 256)) + cg;
        const uint4* a1 = (const uint4*)(T2 + (size_t)(((int)((half >>  8) & 0xFF) * 32 + c0 + 1) * 256)) + cg;
        const uint4* a2 = (const uint4*)(T2 + (size_t)(((int)((half >> 16) & 0xFF) * 32 + c0 + 2) * 256)) + cg;
        const uint4* a3 = (const uint4*)(T2 + (size_t)(((int)( half >> 24        ) * 32 + c0 + 3) * 256)) + cg;
        const uint4 l0 = *a0;
        const uint4 l1 = *a1;
        const uint4 l2 = *a2;
        const uint4 l3 = *a3;
        uint4 sm;   // packed u16x2 adds, fields can't overflow (<= 51808)
        sm.x = l0.x + l1.x + l2.x + l3.x;
        sm.y = l0.y + l1.y + l2.y + l3.y;
        sm.z = l0.z + l1.z + l2.z + l3.z;
        sm.w = l0.w + l1.w + l2.w + l3.w;
        *(uint4*)&part[rg][cg * 8] = sm;
        __syncthreads();                                   // B_mid
        int idx = 0;
#pragma unroll
        for (int r = 0; r < 8; ++r) idx += part[r][t];
        v = (int)((lrow[idx >> 6] >> (idx & 63)) & 1);
    }

    // readout: out[m][o] = b[o] + sum_j v_j * W[o][j]
    __syncthreads();
    if (t < OUT_N) lout[t] = 0.f;
    __syncthreads();
#pragma unroll
    for (int o = 0; o < OUT_N; ++o) {
        float contrib = v ? rW[o * R_NODES + t] : 0.f;
        for (int off = 32; off > 0; off >>= 1)
            contrib += __shfl_down(contrib, off, 64);
        if (lane == 0) atomicAdd(&lout[o], contrib);
    }
    __syncthreads();
    if (t < OUT_N) out[m * OUT_N + t] = lout[t] + rb[t];
}

extern "C" void kernel_launch(void* const* d_in, const int* in_sizes, int n_in,
                              void* d_out, int out_size, void* d_ws, size_t ws_size,
                              hipStream_t stream) {
    const uint8_t* x        = (const uint8_t*)d_in[0];   // bool [M,S,D,B]
    const int* input_nodes  = (const int*)d_in[1];       // int32 [32]
    const int* lut          = (const int*)d_in[2];       // int32 [256, 2^18]
    const uint8_t* wres     = (const uint8_t*)d_in[3];   // bool [256,256]
    const int* primes       = (const int*)d_in[4];       // int32 [256]
    const uint8_t* init_res = (const uint8_t*)d_in[5];   // bool [256]
    const float* rW         = (const float*)d_in[6];     // f32 [10,256]
    const float* rb         = (const float*)d_in[7];     // f32 [10]
    float* out              = (float*)d_out;             // f32 [512,10]

    uint8_t* ws = (uint8_t*)d_ws;
    int*      flag = (int*)ws;                                        // 4 B
    uint32_t* xp   = (uint32_t*)(ws + 4096);                          // 1 MB
    uint16_t* T2   = (uint16_t*)(ws + 4096 + 1048576);                // 4 MB
    uint64_t* lp   = (uint64_t*)(ws + 4096 + 1048576 + 4194304);      // 8 MB

    detect_layout<<<1, 256, 0, stream>>>(x, flag);
    pack_x<<<(M_SAMP * S_STEPS * 32) / 256, 256, 0, stream>>>(x, flag, xp);
    build_T2<<<dim3(256, 32), 256, 0, stream>>>(wres, primes, flag, T2);
    pack_lut<<<512, 256, 0, stream>>>(lut, (uint32_t*)lp);
    reservoir_main<<<M_SAMP, 256, 0, stream>>>(xp, T2, lp, input_nodes, init_res,
                                               flag, rW, rb, out);
}